// Round 1
// baseline (296.502 us; speedup 1.0000x reference)
//
#include <hip/hip_runtime.h>
#include <hip/hip_bf16.h>
#include <stdint.h>

#define T_TOK 8192
#define D_IN  512
#define DINT  256
#define NE    8
#define BM    64
#define MAX_TILES (T_TOK / BM)   // 128

typedef float f32x4 __attribute__((ext_vector_type(4)));
typedef short bf16x8 __attribute__((ext_vector_type(8)));
typedef unsigned short u16;
typedef unsigned short u16x4 __attribute__((ext_vector_type(4)));

// ws layout (bytes)
#define WS_CNT   0
#define WS_BTOK  1024
#define WS_BW    263168      // 1024 + 8*8192*4
#define WS_XB    525312      // + 8*8192*4
#define WS_F1B   8913920     // + 8192*512*2
#define WS_F2B   13108224    // + 8*512*512*2
// end: 15205376 bytes needed in ws

static __device__ __forceinline__ u16 f32_bf16(float f) {
    union { float f; uint32_t u; } v; v.f = f;
    uint32_t u = v.u;
    uint32_t r = (u + 0x7FFFu + ((u >> 16) & 1u)) >> 16;   // RTNE
    return (u16)r;
}

// ---------------- 1. f32 -> bf16 conversion of x, fc1, fc2 ----------------
__global__ __launch_bounds__(256) void cvt_kernel(
    const float* __restrict__ x, const float* __restrict__ fc1,
    const float* __restrict__ fc2, u16* __restrict__ xb,
    u16* __restrict__ f1b, u16* __restrict__ f2b)
{
    const int NX = T_TOK * D_IN / 4;          // 1,048,576 float4
    const int N1 = NE * 2 * DINT * D_IN / 4;  //   524,288
    const int N2 = NE * D_IN * DINT / 4;      //   262,144
    const int total = NX + N1 + N2;
    for (int i = blockIdx.x * 256 + threadIdx.x; i < total; i += gridDim.x * 256) {
        const float4* s; u16* d; int j;
        if (i < NX)            { s = (const float4*)x;   d = xb;  j = i; }
        else if (i < NX + N1)  { s = (const float4*)fc1; d = f1b; j = i - NX; }
        else                   { s = (const float4*)fc2; d = f2b; j = i - NX - N1; }
        float4 v = s[j];
        u16x4 o;
        o.x = f32_bf16(v.x); o.y = f32_bf16(v.y);
        o.z = f32_bf16(v.z); o.w = f32_bf16(v.w);
        *(u16x4*)&d[(size_t)j * 4] = o;
    }
}

// ---------------- 2. gate: softmax + top-2 + bucket scatter ----------------
__global__ __launch_bounds__(256) void gate_kernel(
    const float* __restrict__ x, const float* __restrict__ wg,
    int* __restrict__ cnt, int* __restrict__ btok, float* __restrict__ bw)
{
    __shared__ float wgl[NE * D_IN];   // 16 KB
    const int tid = threadIdx.x;
    for (int i = tid; i < NE * D_IN; i += 256) wgl[i] = wg[i];
    __syncthreads();

    const int wave = tid >> 6, lane = tid & 63;
    const int t = blockIdx.x * 4 + wave;

    float acc[NE];
#pragma unroll
    for (int e = 0; e < NE; e++) acc[e] = 0.f;
    const float* xr = x + (size_t)t * D_IN;
#pragma unroll
    for (int i = 0; i < D_IN / 64; i++) {
        float xi = xr[lane + i * 64];
#pragma unroll
        for (int e = 0; e < NE; e++) acc[e] += xi * wgl[e * D_IN + lane + i * 64];
    }
#pragma unroll
    for (int e = 0; e < NE; e++) {
        float v = acc[e];
#pragma unroll
        for (int off = 32; off; off >>= 1) v += __shfl_xor(v, off);
        acc[e] = v;
    }
    if (lane == 0) {
        float m = acc[0];
#pragma unroll
        for (int e = 1; e < NE; e++) m = fmaxf(m, acc[e]);
        float p[NE], s = 0.f;
#pragma unroll
        for (int e = 0; e < NE; e++) { p[e] = expf(acc[e] - m); s += p[e]; }
        float inv = 1.f / s;
        int i1 = 0; float v1 = p[0];
#pragma unroll
        for (int e = 1; e < NE; e++) if (p[e] > v1) { v1 = p[e]; i1 = e; }
        int i2 = -1; float v2 = -1.f;
#pragma unroll
        for (int e = 0; e < NE; e++) if (e != i1 && p[e] > v2) { v2 = p[e]; i2 = e; }
        int pos1 = atomicAdd(&cnt[i1], 1);
        btok[i1 * T_TOK + pos1] = t; bw[i1 * T_TOK + pos1] = v1 * inv;
        int pos2 = atomicAdd(&cnt[i2], 1);
        btok[i2 * T_TOK + pos2] = t; bw[i2 * T_TOK + pos2] = v2 * inv;
    }
}

// ---------------- 3. fused expert FFN: fc1 -> GLU -> fc2 -> scatter --------
// block = 512 threads (8 waves). Tile: 64 rows (pairs) x full width.
// Stage 1: H = X(64x512) @ fc1[e]^T ; wave w computes y-cols [w*32,w*32+32)
//          and gate-cols [256+w*32, 256+w*32+32) so GLU is register-local.
// Stage 2: O = A(64x256) @ fc2[e]^T ; wave w computes cols [w*64, w*64+64).
#define XST 520   // X LDS stride in bf16 elems (1040B: 2-way bank alias, free)
#define AST 264   // A LDS stride (528B)

__global__ __launch_bounds__(512) void expert_kernel(
    const u16* __restrict__ xb, const u16* __restrict__ f1b,
    const u16* __restrict__ f2b, const int* __restrict__ cnt,
    const int* __restrict__ btok, const float* __restrict__ bw,
    float* __restrict__ out)
{
    const int e    = blockIdx.x >> 7;
    const int tile = blockIdx.x & (MAX_TILES - 1);
    const int n    = cnt[e];
    const int row0 = tile * BM;
    if (row0 >= n) return;
    const int nrows = (n - row0 < BM) ? (n - row0) : BM;

    __shared__ u16 smem[BM * XST];    // 66,560 B; reused for A (BM*AST fits)
    __shared__ int   tok_l[BM];
    __shared__ float w_l[BM];

    const int tid  = threadIdx.x;
    const int wv   = tid >> 6;
    const int lane = tid & 63;
    const int l15  = lane & 15;
    const int lhi  = lane >> 4;

    if (tid < BM) {
        int tk = 0; float ww = 0.f;
        if (tid < nrows) {
            tk = btok[e * T_TOK + row0 + tid];
            ww = bw[e * T_TOK + row0 + tid];
        }
        tok_l[tid] = tk; w_l[tid] = ww;
    }
    __syncthreads();

    // gather X rows (bf16) into LDS
#pragma unroll
    for (int it = 0; it < 16; ++it) {
        int f  = tid + it * 512;
        int r  = f >> 7;          // 128 u16x4-chunks per row
        int c4 = f & 127;
        u16x4 v = *(const u16x4*)&xb[(size_t)tok_l[r] * D_IN + c4 * 4];
        *(u16x4*)&smem[r * XST + c4 * 4] = v;
    }
    __syncthreads();

    // ---- stage 1 ----
    f32x4 acc[4][4];
#pragma unroll
    for (int m = 0; m < 4; m++)
#pragma unroll
        for (int nb = 0; nb < 4; nb++) acc[m][nb] = (f32x4)0.f;

    const u16* w1 = f1b + (size_t)e * 512 * 512;
    int nrow[4];
    nrow[0] = wv * 32 + l15;       nrow[1] = nrow[0] + 16;
    nrow[2] = 256 + wv * 32 + l15; nrow[3] = nrow[2] + 16;

    for (int k0 = 0; k0 < 512; k0 += 32) {
        const int kk = k0 + lhi * 8;
        bf16x8 a[4], b[4];
#pragma unroll
        for (int m = 0; m < 4; m++)
            a[m] = *(const bf16x8*)&smem[(m * 16 + l15) * XST + kk];
#pragma unroll
        for (int nb = 0; nb < 4; nb++)
            b[nb] = *(const bf16x8*)&w1[(size_t)nrow[nb] * 512 + kk];
#pragma unroll
        for (int m = 0; m < 4; m++)
#pragma unroll
            for (int nb = 0; nb < 4; nb++)
                acc[m][nb] = __builtin_amdgcn_mfma_f32_16x16x32_bf16(
                    a[m], b[nb], acc[m][nb], 0, 0, 0);
    }
    __syncthreads();   // everyone done reading X region

    // GLU: a = y * silu(gate), write bf16 A-tile into LDS (reuse smem)
#pragma unroll
    for (int m = 0; m < 4; m++) {
#pragma unroll
        for (int nb = 0; nb < 2; nb++) {
#pragma unroll
            for (int r = 0; r < 4; r++) {
                float y = acc[m][nb][r];
                float g = acc[m][nb + 2][r];
                float aval = y * g / (1.f + __expf(-g));
                int row = m * 16 + lhi * 4 + r;
                int col = wv * 32 + nb * 16 + l15;
                smem[row * AST + col] = f32_bf16(aval);
            }
        }
    }
    __syncthreads();

    // ---- stage 2 ----
    f32x4 acc2[4][4];
#pragma unroll
    for (int m = 0; m < 4; m++)
#pragma unroll
        for (int nb = 0; nb < 4; nb++) acc2[m][nb] = (f32x4)0.f;

    const u16* w2 = f2b + (size_t)e * 512 * 256;
    for (int k0 = 0; k0 < 256; k0 += 32) {
        const int kk = k0 + lhi * 8;
        bf16x8 a[4], b[4];
#pragma unroll
        for (int m = 0; m < 4; m++)
            a[m] = *(const bf16x8*)&smem[(m * 16 + l15) * AST + kk];
#pragma unroll
        for (int nb = 0; nb < 4; nb++)
            b[nb] = *(const bf16x8*)&w2[(size_t)(wv * 64 + nb * 16 + l15) * 256 + kk];
#pragma unroll
        for (int m = 0; m < 4; m++)
#pragma unroll
            for (int nb = 0; nb < 4; nb++)
                acc2[m][nb] = __builtin_amdgcn_mfma_f32_16x16x32_bf16(
                    a[m], b[nb], acc2[m][nb], 0, 0, 0);
    }

    // epilogue: weighted atomic scatter into z
#pragma unroll
    for (int m = 0; m < 4; m++) {
#pragma unroll
        for (int r = 0; r < 4; r++) {
            int row = m * 16 + lhi * 4 + r;
            if (row < nrows) {
                float wt = w_l[row];
                size_t obase = (size_t)tok_l[row] * D_IN + wv * 64 + l15;
#pragma unroll
                for (int nb = 0; nb < 4; nb++)
                    unsafeAtomicAdd(&out[obase + nb * 16], wt * acc2[m][nb][r]);
            }
        }
    }
}

// ---------------- launch ----------------
extern "C" void kernel_launch(void* const* d_in, const int* in_sizes, int n_in,
                              void* d_out, int out_size, void* d_ws, size_t ws_size,
                              hipStream_t stream) {
    const float* x   = (const float*)d_in[0];
    const float* wg  = (const float*)d_in[1];
    const float* fc1 = (const float*)d_in[2];
    const float* fc2 = (const float*)d_in[3];
    float* out = (float*)d_out;
    char* ws = (char*)d_ws;

    int*   cnt  = (int*)(ws + WS_CNT);
    int*   btok = (int*)(ws + WS_BTOK);
    float* bw   = (float*)(ws + WS_BW);
    u16*   xb   = (u16*)(ws + WS_XB);
    u16*   f1b  = (u16*)(ws + WS_F1B);
    u16*   f2b  = (u16*)(ws + WS_F2B);

    hipMemsetAsync(cnt, 0, 1024, stream);
    hipMemsetAsync(d_out, 0, (size_t)T_TOK * D_IN * sizeof(float), stream);

    cvt_kernel<<<2048, 256, 0, stream>>>(x, fc1, fc2, xb, f1b, f2b);
    gate_kernel<<<T_TOK / 4, 256, 0, stream>>>(x, wg, cnt, btok, bw);
    expert_kernel<<<NE * MAX_TILES, 512, 0, stream>>>(xb, f1b, f2b, cnt, btok, bw, out);
}

// Round 2
// 129.469 us; speedup vs baseline: 2.2901x; 2.2901x over previous
//
#include <hip/hip_runtime.h>
#include <hip/hip_bf16.h>
#include <stdint.h>

#define T_TOK 8192
#define D_IN  512
#define DINT  256
#define NE    8
#define BM    64
#define MAX_TILES (T_TOK / BM)   // 128

typedef float f32x4 __attribute__((ext_vector_type(4)));
typedef short bf16x8 __attribute__((ext_vector_type(8)));
typedef unsigned short u16;
typedef unsigned short u16x4 __attribute__((ext_vector_type(4)));

// ws layout (bytes)
#define WS_CNT   0
#define WS_BTOK  1024                      // int slots [NE][T_TOK]
#define WS_WP    (WS_BTOK + NE*T_TOK*4)    // f32 [T_TOK*2] gate weights per slot
#define WS_XB    (WS_WP + T_TOK*2*4)       // bf16 x
#define WS_F1B   (WS_XB + T_TOK*D_IN*2)    // bf16 fc1
#define WS_F2B   (WS_F1B + NE*2*DINT*D_IN*2)
#define WS_OP    (WS_F2B + NE*D_IN*DINT*2) // bf16 out_pairs [T_TOK*2][D_IN]
// end: WS_OP + 16,777,216  ~= 31.8 MB

static __device__ __forceinline__ u16 f32_bf16(float f) {
    union { float f; uint32_t u; } v; v.f = f;
    uint32_t u = v.u;
    uint32_t r = (u + 0x7FFFu + ((u >> 16) & 1u)) >> 16;   // RTNE
    return (u16)r;
}
static __device__ __forceinline__ float bf16_f32(u16 h) {
    union { uint32_t u; float f; } v; v.u = ((uint32_t)h) << 16; return v.f;
}

// ---------------- 1. f32 -> bf16 conversion of x, fc1, fc2 ----------------
__global__ __launch_bounds__(256) void cvt_kernel(
    const float* __restrict__ x, const float* __restrict__ fc1,
    const float* __restrict__ fc2, u16* __restrict__ xb,
    u16* __restrict__ f1b, u16* __restrict__ f2b)
{
    const int NX = T_TOK * D_IN / 4;
    const int N1 = NE * 2 * DINT * D_IN / 4;
    const int N2 = NE * D_IN * DINT / 4;
    const int total = NX + N1 + N2;
    for (int i = blockIdx.x * 256 + threadIdx.x; i < total; i += gridDim.x * 256) {
        const float4* s; u16* d; int j;
        if (i < NX)            { s = (const float4*)x;   d = xb;  j = i; }
        else if (i < NX + N1)  { s = (const float4*)fc1; d = f1b; j = i - NX; }
        else                   { s = (const float4*)fc2; d = f2b; j = i - NX - N1; }
        float4 v = s[j];
        u16x4 o;
        o.x = f32_bf16(v.x); o.y = f32_bf16(v.y);
        o.z = f32_bf16(v.z); o.w = f32_bf16(v.w);
        *(u16x4*)&d[(size_t)j * 4] = o;
    }
}

// ---------------- 2. gate: thread-per-token, LDS-aggregated buckets --------
#define GTOK 256
__global__ __launch_bounds__(256) void gate_kernel(
    const float* __restrict__ x, const float* __restrict__ wg,
    int* __restrict__ cnt, int* __restrict__ btok, float* __restrict__ wpair)
{
    __shared__ float wgl[NE * D_IN];     // 16 KB
    __shared__ float xt[GTOK][66];       // 67.6 KB (one 64-k chunk)
    __shared__ int ecnt[NE];
    __shared__ int gbase[NE];

    const int tid = threadIdx.x;
    const int t0  = blockIdx.x * GTOK;

    for (int i = tid; i < NE * D_IN; i += 256) wgl[i] = wg[i];
    if (tid < NE) ecnt[tid] = 0;

    float acc[NE];
#pragma unroll
    for (int e = 0; e < NE; e++) acc[e] = 0.f;

    for (int c = 0; c < 8; ++c) {
        __syncthreads();
        // stage chunk c: 256 tokens x 64 k (f32), coalesced float2
#pragma unroll 4
        for (int i = 0; i < 32; ++i) {
            int idx = i * 256 + tid;
            int r = idx >> 5, c2 = idx & 31;
            float2 v = *(const float2*)&x[(size_t)(t0 + r) * D_IN + c * 64 + c2 * 2];
            *(float2*)&xt[r][c2 * 2] = v;
        }
        __syncthreads();
#pragma unroll
        for (int k = 0; k < 64; k += 4) {
            float2 xa = *(const float2*)&xt[tid][k];
            float2 xc = *(const float2*)&xt[tid][k + 2];
#pragma unroll
            for (int e = 0; e < NE; e++) {
                float4 w4 = *(const float4*)&wgl[e * D_IN + c * 64 + k];
                acc[e] = fmaf(xa.x, w4.x, fmaf(xa.y, w4.y,
                         fmaf(xc.x, w4.z, fmaf(xc.y, w4.w, acc[e]))));
            }
        }
    }

    // softmax + top-2 (f32, matches reference)
    float m = acc[0];
#pragma unroll
    for (int e = 1; e < NE; e++) m = fmaxf(m, acc[e]);
    float p[NE], s = 0.f;
#pragma unroll
    for (int e = 0; e < NE; e++) { p[e] = expf(acc[e] - m); s += p[e]; }
    float inv = 1.f / s;
    int i1 = 0; float v1 = p[0];
#pragma unroll
    for (int e = 1; e < NE; e++) if (p[e] > v1) { v1 = p[e]; i1 = e; }
    int i2 = -1; float v2 = -1.f;
#pragma unroll
    for (int e = 0; e < NE; e++) if (e != i1 && p[e] > v2) { v2 = p[e]; i2 = e; }

    const int t = t0 + tid;
    wpair[2 * t]     = v1 * inv;
    wpair[2 * t + 1] = v2 * inv;
    int lp1 = atomicAdd(&ecnt[i1], 1);
    int lp2 = atomicAdd(&ecnt[i2], 1);
    __syncthreads();
    if (tid < NE) gbase[tid] = atomicAdd(&cnt[tid], ecnt[tid]);
    __syncthreads();
    btok[i1 * T_TOK + gbase[i1] + lp1] = 2 * t;
    btok[i2 * T_TOK + gbase[i2] + lp2] = 2 * t + 1;
}

// ---------------- 3. fused expert FFN: fc1 -> GLU -> fc2 -> store ----------
#define XST 524   // bf16 stride: word-stride 262 (mod32=6) -> <=2-way banks
#define AST 268   // word-stride 134 (mod32=6)

__global__ __launch_bounds__(512, 2) void expert_kernel(
    const u16* __restrict__ xb, const u16* __restrict__ f1b,
    const u16* __restrict__ f2b, const int* __restrict__ cnt,
    const int* __restrict__ btok, u16* __restrict__ opair)
{
    const int e    = blockIdx.x & 7;          // expert -> XCD pinning
    const int tile = blockIdx.x >> 3;
    const int n    = cnt[e];
    const int row0 = tile * BM;
    if (row0 >= n) return;
    const int nrows = (n - row0 < BM) ? (n - row0) : BM;

    __shared__ u16 smem[BM * XST];    // 67,072 B; A-tile (BM*AST) reuses it
    __shared__ int slot_l[BM];

    const int tid  = threadIdx.x;
    const int wv   = tid >> 6;
    const int lane = tid & 63;
    const int l15  = lane & 15;
    const int lhi  = lane >> 4;

    if (tid < BM)
        slot_l[tid] = (tid < nrows) ? btok[e * T_TOK + row0 + tid] : 0;
    __syncthreads();

    // gather X rows (bf16) into LDS
#pragma unroll
    for (int it = 0; it < 16; ++it) {
        int f  = tid + it * 512;
        int r  = f >> 7;
        int c4 = f & 127;
        u16x4 v = *(const u16x4*)&xb[(size_t)(slot_l[r] >> 1) * D_IN + c4 * 4];
        *(u16x4*)&smem[r * XST + c4 * 4] = v;
    }
    __syncthreads();

    // ---- stage 1: H = X @ fc1^T, wave wv owns y-cols/gate-cols [wv*32,+32) --
    f32x4 acc[4][4];
#pragma unroll
    for (int m = 0; m < 4; m++)
#pragma unroll
        for (int nb = 0; nb < 4; nb++) acc[m][nb] = (f32x4)0.f;

    const u16* w1 = f1b + (size_t)e * (2 * DINT) * D_IN;
    int nrow[4];
    nrow[0] = wv * 32 + l15;        nrow[1] = nrow[0] + 16;
    nrow[2] = 2 * DINT / 2 + wv * 32 + l15; nrow[3] = nrow[2] + 16;

    bf16x8 aA[4], bA[4], aB[4], bB[4];
#define LD1(AR, BR, K) { const int kk = (K) + lhi * 8;                          \
    _Pragma("unroll") for (int m_ = 0; m_ < 4; m_++)                            \
        AR[m_] = *(const bf16x8*)&smem[(m_ * 16 + l15) * XST + kk];             \
    _Pragma("unroll") for (int nb_ = 0; nb_ < 4; nb_++)                         \
        BR[nb_] = *(const bf16x8*)&w1[(size_t)nrow[nb_] * D_IN + kk]; }
#define MM1(AR, BR)                                                             \
    _Pragma("unroll") for (int m_ = 0; m_ < 4; m_++)                            \
    _Pragma("unroll") for (int nb_ = 0; nb_ < 4; nb_++)                         \
        acc[m_][nb_] = __builtin_amdgcn_mfma_f32_16x16x32_bf16(                 \
            AR[m_], BR[nb_], acc[m_][nb_], 0, 0, 0);

    LD1(aA, bA, 0);
#pragma unroll
    for (int k0 = 0; k0 < 512; k0 += 64) {
        LD1(aB, bB, k0 + 32);
        MM1(aA, bA);
        if (k0 + 64 < 512) { LD1(aA, bA, k0 + 64); }
        MM1(aB, bB);
    }
    __syncthreads();   // done reading X region

    // GLU -> bf16 A-tile in LDS
#pragma unroll
    for (int m = 0; m < 4; m++) {
#pragma unroll
        for (int nb = 0; nb < 2; nb++) {
#pragma unroll
            for (int r = 0; r < 4; r++) {
                float y = acc[m][nb][r];
                float g = acc[m][nb + 2][r];
                float aval = y * g / (1.f + __expf(-g));
                int row = m * 16 + lhi * 4 + r;
                int col = wv * 32 + nb * 16 + l15;
                smem[row * AST + col] = f32_bf16(aval);
            }
        }
    }
    __syncthreads();

    // ---- stage 2: O = A @ fc2^T, wave wv owns out-cols [wv*64,+64) ----------
    f32x4 acc2[4][4];
#pragma unroll
    for (int m = 0; m < 4; m++)
#pragma unroll
        for (int nb = 0; nb < 4; nb++) acc2[m][nb] = (f32x4)0.f;

    const u16* w2 = f2b + (size_t)e * D_IN * DINT;
#define LD2(AR, BR, K) { const int kk = (K) + lhi * 8;                          \
    _Pragma("unroll") for (int m_ = 0; m_ < 4; m_++)                            \
        AR[m_] = *(const bf16x8*)&smem[(m_ * 16 + l15) * AST + kk];             \
    _Pragma("unroll") for (int nb_ = 0; nb_ < 4; nb_++)                         \
        BR[nb_] = *(const bf16x8*)&w2[(size_t)(wv * 64 + nb_ * 16 + l15) * DINT + kk]; }
#define MM2(AR, BR)                                                             \
    _Pragma("unroll") for (int m_ = 0; m_ < 4; m_++)                            \
    _Pragma("unroll") for (int nb_ = 0; nb_ < 4; nb_++)                         \
        acc2[m_][nb_] = __builtin_amdgcn_mfma_f32_16x16x32_bf16(                \
            AR[m_], BR[nb_], acc2[m_][nb_], 0, 0, 0);

    LD2(aA, bA, 0);
#pragma unroll
    for (int k0 = 0; k0 < 256; k0 += 64) {
        LD2(aB, bB, k0 + 32);
        MM2(aA, bA);
        if (k0 + 64 < 256) { LD2(aA, bA, k0 + 64); }
        MM2(aB, bB);
    }

    // epilogue: plain bf16 stores into out_pairs[slot]
#pragma unroll
    for (int m = 0; m < 4; m++) {
#pragma unroll
        for (int r = 0; r < 4; r++) {
            int row = m * 16 + lhi * 4 + r;
            if (row < nrows) {
                u16* orow = opair + (size_t)slot_l[row] * D_IN + wv * 64 + l15;
#pragma unroll
                for (int nb = 0; nb < 4; nb++)
                    orow[nb * 16] = f32_bf16(acc2[m][nb][r]);
            }
        }
    }
#undef LD1
#undef MM1
#undef LD2
#undef MM2
}

// ---------------- 4. combine: z[t] = w0*o[t,0] + w1*o[t,1] -----------------
__global__ __launch_bounds__(256) void combine_kernel(
    const u16* __restrict__ opair, const float* __restrict__ wpair,
    float* __restrict__ out)
{
    int idx = blockIdx.x * 256 + threadIdx.x;    // over T_TOK * 64 chunks
    int t  = idx >> 6;
    int c8 = (idx & 63) * 8;
    float w0 = wpair[2 * t], w1 = wpair[2 * t + 1];
    bf16x8 a = *(const bf16x8*)&opair[(size_t)(2 * t) * D_IN + c8];
    bf16x8 b = *(const bf16x8*)&opair[(size_t)(2 * t + 1) * D_IN + c8];
    float4 o0, o1;
#pragma unroll
    for (int j = 0; j < 4; j++) {
        o0[j] = w0 * bf16_f32((u16)a[j])     + w1 * bf16_f32((u16)b[j]);
        o1[j] = w0 * bf16_f32((u16)a[j + 4]) + w1 * bf16_f32((u16)b[j + 4]);
    }
    float* orow = out + (size_t)t * D_IN + c8;
    *(float4*)orow = o0;
    *(float4*)(orow + 4) = o1;
}

// ---------------- launch ----------------
extern "C" void kernel_launch(void* const* d_in, const int* in_sizes, int n_in,
                              void* d_out, int out_size, void* d_ws, size_t ws_size,
                              hipStream_t stream) {
    const float* x   = (const float*)d_in[0];
    const float* wg  = (const float*)d_in[1];
    const float* fc1 = (const float*)d_in[2];
    const float* fc2 = (const float*)d_in[3];
    float* out = (float*)d_out;
    char* ws = (char*)d_ws;

    int*   cnt   = (int*)(ws + WS_CNT);
    int*   btok  = (int*)(ws + WS_BTOK);
    float* wpair = (float*)(ws + WS_WP);
    u16*   xb    = (u16*)(ws + WS_XB);
    u16*   f1b   = (u16*)(ws + WS_F1B);
    u16*   f2b   = (u16*)(ws + WS_F2B);
    u16*   opair = (u16*)(ws + WS_OP);

    hipMemsetAsync(cnt, 0, 1024, stream);

    cvt_kernel<<<2048, 256, 0, stream>>>(x, fc1, fc2, xb, f1b, f2b);
    gate_kernel<<<T_TOK / GTOK, 256, 0, stream>>>(x, wg, cnt, btok, wpair);
    expert_kernel<<<NE * MAX_TILES, 512, 0, stream>>>(xb, f1b, f2b, cnt, btok, opair);
    combine_kernel<<<T_TOK * (D_IN / 8) / 256, 256, 0, stream>>>(opair, wpair, out);
}

// Round 3
// 107.778 us; speedup vs baseline: 2.7511x; 1.2013x over previous
//
#include <hip/hip_runtime.h>
#include <hip/hip_bf16.h>
#include <stdint.h>

#define T_TOK 8192
#define D_IN  512
#define DINT  256
#define NE    8
#define BM    64

typedef float f32x4 __attribute__((ext_vector_type(4)));
typedef short bf16x8 __attribute__((ext_vector_type(8)));
typedef unsigned short u16;
typedef unsigned short u16x4 __attribute__((ext_vector_type(4)));

// ws layout (bytes)
#define WS_CNT   0
#define WS_BTOK  1024                      // int slots [NE][T_TOK]
#define WS_WP    (WS_BTOK + NE*T_TOK*4)    // f32 [T_TOK*2]
#define WS_XB    (WS_WP + T_TOK*2*4)       // bf16 x
#define WS_F1B   (WS_XB + T_TOK*D_IN*2)    // bf16 fc1
#define WS_F2B   (WS_F1B + NE*2*DINT*D_IN*2)
#define WS_OP    (WS_F2B + NE*D_IN*DINT*2) // bf16 out_pairs [T_TOK*2][D_IN]

typedef const __attribute__((address_space(1))) void* gptr_t;
typedef __attribute__((address_space(3))) void* lptr_t;
#define GLL16(g, s) __builtin_amdgcn_global_load_lds((gptr_t)(g), (lptr_t)(s), 16, 0, 0)

static __device__ __forceinline__ u16 f32_bf16(float f) {
    union { float f; uint32_t u; } v; v.f = f;
    uint32_t u = v.u;
    uint32_t r = (u + 0x7FFFu + ((u >> 16) & 1u)) >> 16;   // RTNE
    return (u16)r;
}
static __device__ __forceinline__ float bf16_f32(u16 h) {
    union { uint32_t u; float f; } v; v.u = ((uint32_t)h) << 16; return v.f;
}

// ---------------- 1. f32 -> bf16 conversion ----------------
__global__ __launch_bounds__(256) void cvt_kernel(
    const float* __restrict__ x, const float* __restrict__ fc1,
    const float* __restrict__ fc2, u16* __restrict__ xb,
    u16* __restrict__ f1b, u16* __restrict__ f2b)
{
    const int NX = T_TOK * D_IN / 4;
    const int N1 = NE * 2 * DINT * D_IN / 4;
    const int N2 = NE * D_IN * DINT / 4;
    const int total = NX + N1 + N2;
    for (int i = blockIdx.x * 256 + threadIdx.x; i < total; i += gridDim.x * 256) {
        const float4* s; u16* d; int j;
        if (i < NX)            { s = (const float4*)x;   d = xb;  j = i; }
        else if (i < NX + N1)  { s = (const float4*)fc1; d = f1b; j = i - NX; }
        else                   { s = (const float4*)fc2; d = f2b; j = i - NX - N1; }
        float4 v = s[j];
        u16x4 o;
        o.x = f32_bf16(v.x); o.y = f32_bf16(v.y);
        o.z = f32_bf16(v.z); o.w = f32_bf16(v.w);
        *(u16x4*)&d[(size_t)j * 4] = o;
    }
}

// ---------------- 2. gate: 64 tokens/block, 4-way k-split ----------------
__global__ __launch_bounds__(256) void gate_kernel(
    const float* __restrict__ x, const float* __restrict__ wg,
    int* __restrict__ cnt, int* __restrict__ btok, float* __restrict__ wpair)
{
    __shared__ float wgl[NE * D_IN];     // 16 KB
    __shared__ float part[256 * 9];      // 9 KB, stride 9 -> conflict-free
    __shared__ int ecnt[NE];
    __shared__ int gbase[NE];

    const int tid = threadIdx.x;
    const int tl  = tid & 63;
    const int kq  = tid >> 6;            // k-quarter 0..3
    const int t   = blockIdx.x * 64 + tl;

    for (int i = tid; i < NE * D_IN; i += 256) wgl[i] = wg[i];
    if (tid < NE) ecnt[tid] = 0;
    __syncthreads();

    float acc[NE];
#pragma unroll
    for (int e = 0; e < NE; e++) acc[e] = 0.f;
    const float* xr = x + (size_t)t * D_IN + kq * 128;
#pragma unroll
    for (int i = 0; i < 32; ++i) {
        float4 v = *(const float4*)&xr[i * 4];
#pragma unroll
        for (int e = 0; e < NE; e++) {
            float4 w = *(const float4*)&wgl[e * D_IN + kq * 128 + i * 4];
            acc[e] = fmaf(v.x, w.x, fmaf(v.y, w.y,
                     fmaf(v.z, w.z, fmaf(v.w, w.w, acc[e]))));
        }
    }
#pragma unroll
    for (int e = 0; e < NE; e++) part[tid * 9 + e] = acc[e];
    __syncthreads();

    int i1 = 0, i2 = -1, lp1 = 0, lp2 = 0;
    if (tid < 64) {
        float s8[NE];
#pragma unroll
        for (int e = 0; e < NE; e++)
            s8[e] = part[tid * 9 + e] + part[(64 + tid) * 9 + e]
                  + part[(128 + tid) * 9 + e] + part[(192 + tid) * 9 + e];
        float m = s8[0];
#pragma unroll
        for (int e = 1; e < NE; e++) m = fmaxf(m, s8[e]);
        float p[NE], s = 0.f;
#pragma unroll
        for (int e = 0; e < NE; e++) { p[e] = expf(s8[e] - m); s += p[e]; }
        float inv = 1.f / s;
        float v1 = p[0];
#pragma unroll
        for (int e = 1; e < NE; e++) if (p[e] > v1) { v1 = p[e]; i1 = e; }
        float v2 = -1.f;
#pragma unroll
        for (int e = 0; e < NE; e++) if (e != i1 && p[e] > v2) { v2 = p[e]; i2 = e; }
        wpair[2 * t]     = v1 * inv;
        wpair[2 * t + 1] = v2 * inv;
        lp1 = atomicAdd(&ecnt[i1], 1);
        lp2 = atomicAdd(&ecnt[i2], 1);
    }
    __syncthreads();
    if (tid < NE) gbase[tid] = atomicAdd(&cnt[tid], ecnt[tid]);
    __syncthreads();
    if (tid < 64) {
        btok[i1 * T_TOK + gbase[i1] + lp1] = 2 * t;
        btok[i2 * T_TOK + gbase[i2] + lp2] = 2 * t + 1;
    }
}

// ---------------- 3. fused expert FFN (m97-style LDS-staged B) -------------
// LDS: X [64][520] padded (16B-aligned rows, 2-way alias) = 66,560 B
//      B  dbuf 2 x 32KB, layout grp(col>>4)*1024B + k8*256B + (col&15)*16B
//        -> fragment read = contiguous 1KB per wave (conflict-free)
#define XST 520
#define AST 264

__global__ __launch_bounds__(512) void expert_kernel(
    const u16* __restrict__ xb, const u16* __restrict__ f1b,
    const u16* __restrict__ f2b, const int* __restrict__ cnt,
    const int* __restrict__ btok, u16* __restrict__ opair)
{
    __shared__ __align__(16) u16 xs[BM * XST];        // 66,560 B (A-tile reuses)
    __shared__ __align__(16) u16 bbuf[2][16384];      // 65,536 B
    __shared__ int slot_l[BM];

    // --- map linear block id -> (expert, tile) via prefix over cnt ---
    const int bid = blockIdx.x;
    int e = 0, tile = 0, accn = 0, found = 0;
#pragma unroll
    for (int ee = 0; ee < NE; ee++) {
        int nt = (cnt[ee] + BM - 1) >> 6;
        if (!found && bid < accn + nt) { e = ee; tile = bid - accn; found = 1; }
        accn += nt;
    }
    if (!found) return;

    const int n     = cnt[e];
    const int row0  = tile * BM;
    const int nrows = (n - row0 < BM) ? (n - row0) : BM;

    const int tid  = threadIdx.x;
    const int wv   = tid >> 6;
    const int lane = tid & 63;
    const int l15  = lane & 15;
    const int lhi  = lane >> 4;

    if (tid < BM)
        slot_l[tid] = btok[e * T_TOK + row0 + ((tid < nrows) ? tid : 0)];
    __syncthreads();

    // gather X rows (bf16) into LDS, 16B chunks
#pragma unroll
    for (int it = 0; it < 8; ++it) {
        int idx = tid + it * 512;
        int r = idx >> 6, c16 = idx & 63;
        bf16x8 v = *(const bf16x8*)&xb[(size_t)(slot_l[r] >> 1) * D_IN + c16 * 8];
        *(bf16x8*)&xs[r * XST + c16 * 8] = v;
    }

    const u16* w1 = f1b + (size_t)e * (2 * DINT) * D_IN;
    const u16* w2 = f2b + (size_t)e * D_IN * DINT;

#define STAGE(BUF, WBASE, KROW, K0)                                             \
    { _Pragma("unroll") for (int j_ = 0; j_ < 4; j_++) {                        \
        const int col_ = (wv * 4 + j_) * 16 + l15;                              \
        GLL16(&(WBASE)[(size_t)col_ * (KROW) + (K0) + lhi * 8],                 \
              &bbuf[BUF][(wv * 4 + j_) * 512]); } }

    // ---- stage 1: H = X @ fc1^T ----
    f32x4 acc[4][4];
#pragma unroll
    for (int m = 0; m < 4; m++)
#pragma unroll
        for (int nb = 0; nb < 4; nb++) acc[m][nb] = (f32x4)0.f;

    int grp1[4] = { wv * 2, wv * 2 + 1, 16 + wv * 2, 17 + wv * 2 };

    STAGE(0, w1, D_IN, 0);
    int cur = 0;
#pragma unroll
    for (int k0 = 0; k0 < D_IN; k0 += 32) {
        __syncthreads();                       // bbuf[cur] (and xs, 1st iter) ready
        if (k0 + 32 < D_IN) STAGE(cur ^ 1, w1, D_IN, k0 + 32);
        bf16x8 a[4], b[4];
#pragma unroll
        for (int m = 0; m < 4; m++)
            a[m] = *(const bf16x8*)&xs[(m * 16 + l15) * XST + k0 + lhi * 8];
#pragma unroll
        for (int nb = 0; nb < 4; nb++)
            b[nb] = *(const bf16x8*)&bbuf[cur][grp1[nb] * 512 + lane * 8];
#pragma unroll
        for (int m = 0; m < 4; m++)
#pragma unroll
            for (int nb = 0; nb < 4; nb++)
                acc[m][nb] = __builtin_amdgcn_mfma_f32_16x16x32_bf16(
                    a[m], b[nb], acc[m][nb], 0, 0, 0);
        cur ^= 1;
    }

    STAGE(0, w2, DINT, 0);                      // prefetch stage2 slice 0
    __syncthreads();                            // all stage1 reads of xs done

    // GLU -> bf16 A-tile into xs region (AST layout)
#pragma unroll
    for (int m = 0; m < 4; m++) {
#pragma unroll
        for (int nb = 0; nb < 2; nb++) {
#pragma unroll
            for (int r = 0; r < 4; r++) {
                float y = acc[m][nb][r];
                float g = acc[m][nb + 2][r];
                float aval = y * g / (1.f + __expf(-g));
                int row = m * 16 + lhi * 4 + r;
                int col = wv * 32 + nb * 16 + l15;
                xs[row * AST + col] = f32_bf16(aval);
            }
        }
    }

    // ---- stage 2: O = A @ fc2^T ----
    f32x4 acc2[4][4];
#pragma unroll
    for (int m = 0; m < 4; m++)
#pragma unroll
        for (int nb = 0; nb < 4; nb++) acc2[m][nb] = (f32x4)0.f;

    cur = 0;
#pragma unroll
    for (int k0 = 0; k0 < DINT; k0 += 32) {
        __syncthreads();                       // A-tile written + bbuf[cur] ready
        if (k0 + 32 < DINT) STAGE(cur ^ 1, w2, DINT, k0 + 32);
        bf16x8 a[4], b[4];
#pragma unroll
        for (int m = 0; m < 4; m++)
            a[m] = *(const bf16x8*)&xs[(m * 16 + l15) * AST + k0 + lhi * 8];
#pragma unroll
        for (int nb = 0; nb < 4; nb++)
            b[nb] = *(const bf16x8*)&bbuf[cur][(wv * 4 + nb) * 512 + lane * 8];
#pragma unroll
        for (int m = 0; m < 4; m++)
#pragma unroll
            for (int nb = 0; nb < 4; nb++)
                acc2[m][nb] = __builtin_amdgcn_mfma_f32_16x16x32_bf16(
                    a[m], b[nb], acc2[m][nb], 0, 0, 0);
        cur ^= 1;
    }

    // epilogue: plain bf16 stores into out_pairs[slot]
#pragma unroll
    for (int m = 0; m < 4; m++) {
#pragma unroll
        for (int r = 0; r < 4; r++) {
            int row = m * 16 + lhi * 4 + r;
            if (row < nrows) {
                u16* orow = opair + (size_t)slot_l[row] * D_IN + wv * 64 + l15;
#pragma unroll
                for (int nb = 0; nb < 4; nb++)
                    orow[nb * 16] = f32_bf16(acc2[m][nb][r]);
            }
        }
    }
#undef STAGE
}

// ---------------- 4. combine ----------------
__global__ __launch_bounds__(256) void combine_kernel(
    const u16* __restrict__ opair, const float* __restrict__ wpair,
    float* __restrict__ out)
{
    int idx = blockIdx.x * 256 + threadIdx.x;
    int t  = idx >> 6;
    int c8 = (idx & 63) * 8;
    float w0 = wpair[2 * t], w1 = wpair[2 * t + 1];
    bf16x8 a = *(const bf16x8*)&opair[(size_t)(2 * t) * D_IN + c8];
    bf16x8 b = *(const bf16x8*)&opair[(size_t)(2 * t + 1) * D_IN + c8];
    float4 o0, o1;
#pragma unroll
    for (int j = 0; j < 4; j++) {
        o0[j] = w0 * bf16_f32((u16)a[j])     + w1 * bf16_f32((u16)b[j]);
        o1[j] = w0 * bf16_f32((u16)a[j + 4]) + w1 * bf16_f32((u16)b[j + 4]);
    }
    float* orow = out + (size_t)t * D_IN + c8;
    *(float4*)orow = o0;
    *(float4*)(orow + 4) = o1;
}

// ---------------- launch ----------------
extern "C" void kernel_launch(void* const* d_in, const int* in_sizes, int n_in,
                              void* d_out, int out_size, void* d_ws, size_t ws_size,
                              hipStream_t stream) {
    const float* x   = (const float*)d_in[0];
    const float* wg  = (const float*)d_in[1];
    const float* fc1 = (const float*)d_in[2];
    const float* fc2 = (const float*)d_in[3];
    float* out = (float*)d_out;
    char* ws = (char*)d_ws;

    int*   cnt   = (int*)(ws + WS_CNT);
    int*   btok  = (int*)(ws + WS_BTOK);
    float* wpair = (float*)(ws + WS_WP);
    u16*   xb    = (u16*)(ws + WS_XB);
    u16*   f1b   = (u16*)(ws + WS_F1B);
    u16*   f2b   = (u16*)(ws + WS_F2B);
    u16*   opair = (u16*)(ws + WS_OP);

    hipMemsetAsync(cnt, 0, 1024, stream);

    cvt_kernel<<<2048, 256, 0, stream>>>(x, fc1, fc2, xb, f1b, f2b);
    gate_kernel<<<T_TOK / 64, 256, 0, stream>>>(x, wg, cnt, btok, wpair);
    expert_kernel<<<263, 512, 0, stream>>>(xb, f1b, f2b, cnt, btok, opair);
    combine_kernel<<<T_TOK * (D_IN / 8) / 256, 256, 0, stream>>>(opair, wpair, out);
}